// Round 2
// baseline (78.369 us; speedup 1.0000x reference)
//
#include <hip/hip_runtime.h>
#include <hip/hip_bf16.h>

#define NNODES 100000
#define NHE 20000
#define NEDGES 600000

typedef float f32x4 __attribute__((ext_vector_type(4)));
typedef short bf16x8 __attribute__((ext_vector_type(8)));
typedef short bf16x4 __attribute__((ext_vector_type(4)));

__device__ __forceinline__ unsigned short f2bf(float f) {
    unsigned u = __builtin_bit_cast(unsigned, f);
    u += 0x7fffu + ((u >> 16) & 1u);
    return (unsigned short)(u >> 16);
}

// Fused: init last[] to -1, and build wt = W_f^T as bf16, layout [c][k] (c<128, k<256)
__global__ void k_setup(int* __restrict__ last, const float* __restrict__ Wf,
                        unsigned short* __restrict__ wt) {
    int b = blockIdx.x, t = threadIdx.x;
    if (b < 391) {
        int i = b * 256 + t;
        if (i < NNODES) last[i] = -1;
    } else {
        int idx = (b - 391) * 256 + t;   // 0..32767
        int k = idx >> 7, c = idx & 127;
        wt[c * 256 + k] = f2bf(Wf[idx]);
    }
}

__global__ void k_scatter(const int* __restrict__ sl, int* __restrict__ last) {
    int e = blockIdx.x * 256 + threadIdx.x;
    if (e < NEDGES) atomicMax(&last[sl[3 * e]], e);
}

// out[100000][128] = valid ? [h_emb | node_emb] @ W_f : 0
// BM=64, N=128, K=256 in 4 chunks of 64. 256 threads = 4 waves (2M x 2N),
// wave tile 32x64 via 2x4 fragments of mfma_f32_16x16x32_bf16.
// X double-buffered in LDS; W fragments read directly from global wt image.
__global__ __launch_bounds__(256) void k_main(
    const float* __restrict__ node_emb,
    const float* __restrict__ he_emb,
    const int* __restrict__ sl,
    const int* __restrict__ last,
    const unsigned short* __restrict__ wt,
    float* __restrict__ out)
{
    __shared__ __align__(16) unsigned short Xs[2][64 * 64];  // 2 x 8KB, swizzled
    __shared__ int he_s[64];
    __shared__ int valid_s[64];

    int t = threadIdx.x;
    int r0 = blockIdx.x * 64;

    if (t < 64) {
        int ri = r0 + t;
        int e = (ri < NNODES) ? last[ri] : -1;
        int v = (e >= 0) ? 1 : 0;
        valid_s[t] = v;
        he_s[t] = v ? sl[3 * e + 2] : 0;
    }
    __syncthreads();

    int lane = t & 63, w = t >> 6;
    int wm = w >> 1, wn = w & 1;
    int l15 = lane & 15, l4 = lane >> 4;
    int tr = t >> 4, q = t & 15;    // staging: row-group / quad within row

    f32x4 acc[2][4] = {};
    f32x4 pre[4];

    // ---- prefetch chunk 0 ----
    #pragma unroll
    for (int i = 0; i < 4; ++i) {
        int row = i * 16 + tr;
        pre[i] = *(const f32x4*)(he_emb + he_s[row] * 128 + q * 4);
    }

    #pragma unroll
    for (int kc = 0; kc < 4; ++kc) {
        // ---- write staged chunk kc (regs -> LDS, f32 -> bf16, swizzled) ----
        #pragma unroll
        for (int i = 0; i < 4; ++i) {
            int row = i * 16 + tr;
            bf16x4 p;
            p[0] = (short)f2bf(pre[i][0]);
            p[1] = (short)f2bf(pre[i][1]);
            p[2] = (short)f2bf(pre[i][2]);
            p[3] = (short)f2bf(pre[i][3]);
            int byte = (row * 128 + q * 8) ^ ((row & 7) << 4);
            *(bf16x4*)((char*)Xs[kc & 1] + byte) = p;
        }
        // ---- issue prefetch for chunk kc+1 (latency spans barrier+compute) ----
        if (kc < 3) {
            int kn = kc + 1;
            #pragma unroll
            for (int i = 0; i < 4; ++i) {
                int row = i * 16 + tr;
                const float* s;
                if (kn < 2) {
                    s = he_emb + he_s[row] * 128 + kn * 64 + q * 4;
                } else {
                    int ri = r0 + row;
                    if (ri >= NNODES) ri = NNODES - 1;
                    s = node_emb + ri * 128 + (kn - 2) * 64 + q * 4;
                }
                pre[i] = *(const f32x4*)s;
            }
        }
        // ---- barrier: drain LDS writes only; leave global prefetch in flight ----
        asm volatile("s_waitcnt lgkmcnt(0)" ::: "memory");
        __builtin_amdgcn_sched_barrier(0);
        __builtin_amdgcn_s_barrier();
        __builtin_amdgcn_sched_barrier(0);

        // ---- compute chunk kc: 2 K=32 steps, 16 MFMA ----
        #pragma unroll
        for (int ks = 0; ks < 2; ++ks) {
            bf16x8 a[2], b[4];
            #pragma unroll
            for (int fm = 0; fm < 2; ++fm) {
                int row = wm * 32 + fm * 16 + l15;
                int byte = (row * 128 + ks * 64 + l4 * 16) ^ ((row & 7) << 4);
                a[fm] = *(const bf16x8*)((const char*)Xs[kc & 1] + byte);
            }
            #pragma unroll
            for (int fn = 0; fn < 4; ++fn) {
                int col = wn * 64 + fn * 16 + l15;
                b[fn] = *(const bf16x8*)(wt + col * 256 + kc * 64 + ks * 32 + l4 * 8);
            }
            #pragma unroll
            for (int fm = 0; fm < 2; ++fm)
                #pragma unroll
                for (int fn = 0; fn < 4; ++fn)
                    acc[fm][fn] = __builtin_amdgcn_mfma_f32_16x16x32_bf16(
                        a[fm], b[fn], acc[fm][fn], 0, 0, 0);
        }
        // next iteration's LDS write targets the other buffer; the barrier above
        // (next iter) orders write-after-read on this buffer two iters out.
    }

    // ---- epilogue: D lane map col=lane&15, row=(lane>>4)*4+j ----
    #pragma unroll
    for (int fm = 0; fm < 2; ++fm) {
        #pragma unroll
        for (int j = 0; j < 4; ++j) {
            int lrow = wm * 32 + fm * 16 + l4 * 4 + j;
            int ri = r0 + lrow;
            if (ri < NNODES) {
                int v = valid_s[lrow];
                #pragma unroll
                for (int fn = 0; fn < 4; ++fn) {
                    int col = wn * 64 + fn * 16 + l15;
                    out[ri * 128 + col] = v ? acc[fm][fn][j] : 0.0f;
                }
            }
        }
    }
}

extern "C" void kernel_launch(void* const* d_in, const int* in_sizes, int n_in,
                              void* d_out, int out_size, void* d_ws, size_t ws_size,
                              hipStream_t stream) {
    const float* node_emb = (const float*)d_in[0];
    // d_in[1] = semalink_embeddings : dead (softmax over size-1 axis -> gamma == 1)
    const float* he_emb = (const float*)d_in[2];
    const int* sl = (const int*)d_in[3];
    // d_in[4] = W_a : dead
    const float* Wf = (const float*)d_in[5];
    float* out = (float*)d_out;

    int* last = (int*)d_ws;                                        // 400000 B
    unsigned short* wt = (unsigned short*)((char*)d_ws + 400128);  // 64 KB, aligned

    k_setup<<<519, 256, 0, stream>>>(last, Wf, wt);
    k_scatter<<<(NEDGES + 255) / 256, 256, 0, stream>>>(sl, last);
    k_main<<<(NNODES + 63) / 64, 256, 0, stream>>>(node_emb, he_emb, sl, last, wt, out);
}